// Round 1
// 394.373 us; speedup vs baseline: 1.1015x; 1.1015x over previous
//
#include <hip/hip_runtime.h>
#include <hip/hip_bf16.h>
#include <math.h>

typedef __attribute__((ext_vector_type(4))) float floatx4;
typedef __attribute__((ext_vector_type(16))) float floatx16;
typedef __attribute__((ext_vector_type(8))) __bf16 bf16x8;

__device__ __forceinline__ unsigned short f2bf(float f) {
    union { float f; unsigned int u; } v; v.f = f;
    unsigned int u = v.u;
    u += 0x7FFFu + ((u >> 16) & 1u);          // round-to-nearest-even
    return (unsigned short)(u >> 16);
}

__device__ __forceinline__ unsigned int pkbf(float a, float b) {
    return (unsigned int)f2bf(a) | ((unsigned int)f2bf(b) << 16);  // low16=a
}

// async global->LDS, 16B per lane; lds base must be wave-uniform
__device__ __forceinline__ void gl_lds16(const void* g, void* l) {
    __builtin_amdgcn_global_load_lds(
        (const __attribute__((address_space(1))) void*)g,
        (__attribute__((address_space(3))) void*)l, 16, 0, 0);
}

// ---------------------------------------------------------------- cast kernel
__global__ void cast_f32_bf16(const float* __restrict__ in,
                              unsigned short* __restrict__ out, int n) {
    int i = (blockIdx.x * blockDim.x + threadIdx.x) * 4;
    if (i + 4 <= n) {
        float4 f = *(const float4*)(in + i);
        ushort4 o;
        o.x = f2bf(f.x); o.y = f2bf(f.y); o.z = f2bf(f.z); o.w = f2bf(f.w);
        *(ushort4*)(out + i) = o;
    }
}

// ---------------------------------------------------------------- GEMM (NT)
// C[M,N] = A[M,K] * B[N,K]^T + bias[N]
// 256x256 tile, BK=64, 8 waves (2Mx4N), 8-phase counted-vmcnt schedule
// (T1 XCD swizzle + T2 LDS XOR swizzle + T3/T4 pipeline + T5 setprio).
// LDS: 2 buf x (A 32KB + B 32KB) = 128 KiB dynamic.
// MODE 0: fp32 C.  MODE 1: bf16 scatter to q/k/vT (N==6144 path).

#define VMCNT(n) asm volatile("s_waitcnt vmcnt(" #n ")" ::: "memory")
#define BARF()   do { __builtin_amdgcn_s_barrier(); asm volatile("" ::: "memory"); } while (0)

// stage one 128-row half (h) of a K-tile tt into buffer bsel. 2 x gl_lds16
// per thread: rows c*64 + tid>>3, 16B slot (tid&7) with inverse T2 swizzle
// applied on the GLOBAL source (LDS dest must stay linear for global_load_lds).
#define STAGE_A(bsel, tt, h) do { \
    const unsigned short* _s = Ab + (size_t)((h) * 128 + rstage) * K + (tt) * 64 + scol; \
    char* _d = bufc + (bsel) * 65536 + (h) * 16384 + wid * 1024; \
    gl_lds16(_s, _d); \
    gl_lds16(_s + (size_t)64 * K, _d + 8192); \
} while (0)

#define STAGE_B(bsel, tt, h) do { \
    const unsigned short* _s = Bb + (size_t)((h) * 128 + rstage) * K + (tt) * 64 + scol; \
    char* _d = bufc + (bsel) * 65536 + 32768 + (h) * 16384 + wid * 1024; \
    gl_lds16(_s, _d); \
    gl_lds16(_s + (size_t)64 * K, _d + 8192); \
} while (0)

// swizzled LDS fragment reads (row&7 == lane&7 for every fragment row)
#define RDA(base, ii, kse) (*(const bf16x8*)((base) + (ii) * 2048 + rdoffA + (kse)))
#define RDB(base, jj, kse) (*(const bf16x8*)((base) + (jj) * 2048 + rdoffB + (kse)))

// one quadrant: 8 acc frags x K=64 (2 chained k-substeps) = 16 MFMA
#define MFMA_Q(iofs, jofs, BV) do { \
    __builtin_amdgcn_s_setprio(1); \
    _Pragma("unroll") \
    for (int ii = 0; ii < 4; ++ii) { \
        _Pragma("unroll") \
        for (int jj = 0; jj < 2; ++jj) { \
            acc[(iofs) + ii][(jofs) + jj] = __builtin_amdgcn_mfma_f32_16x16x32_bf16( \
                aF[ii * 2 + 0], BV[jj * 2 + 0], acc[(iofs) + ii][(jofs) + jj], 0, 0, 0); \
            acc[(iofs) + ii][(jofs) + jj] = __builtin_amdgcn_mfma_f32_16x16x32_bf16( \
                aF[ii * 2 + 1], BV[jj * 2 + 1], acc[(iofs) + ii][(jofs) + jj], 0, 0, 0); \
        } } \
    __builtin_amdgcn_s_setprio(0); \
} while (0)

template<int MODE>
__global__ __launch_bounds__(512, 2) void gemm8p(
    const unsigned short* __restrict__ A,
    const unsigned short* __restrict__ B,
    const float* __restrict__ bias,
    float* __restrict__ Cf,
    unsigned short* __restrict__ q_ws,
    unsigned short* __restrict__ k_ws,
    unsigned short* __restrict__ vT_ws,
    int M, int N, int K)
{
    extern __shared__ char ldsc[];
    char* const bufc = ldsc;

    // T1: bijective XCD swizzle (nwg % 8 == 0 for both call sites); within an
    // XCD chunk, by cycles fastest -> each XCD reuses a few B panels in its L2.
    const int nby = M >> 8;
    const int nwg = gridDim.x;
    const int qq = nwg >> 3;
    const int wg = (blockIdx.x & 7) * qq + (blockIdx.x >> 3);
    const int by = wg % nby, bx = wg / nby;
    const int m0 = by << 8, n0 = bx << 8;

    const int tid = threadIdx.x;
    const int lane = tid & 63, wid = tid >> 6;
    const int li = lane & 15, quad = lane >> 4;
    const int wr = wid >> 2, wc = wid & 3;          // 2 x 4 wave grid

    // staging geometry (constant per thread across all stages)
    const int rstage = tid >> 3;                                   // 0..63
    const int scol = (((tid & 7) ^ ((tid >> 3) & 7)) << 3);        // swizzled src col (elems)
    const unsigned short* Ab = A + (size_t)m0 * K;
    const unsigned short* Bb = B + (size_t)n0 * K;

    // read-side per-lane offsets (T2 swizzle folded into constants)
    const int swz = (lane & 7) << 4;
    const int ks0 = ((quad << 4)     ) ^ swz;
    const int ks1 = ((quad << 4) + 64) ^ swz;
    const int rdoffA = li * 128;
    const int rdoffB = li * 128 + ((wc & 1) << 13);

    const char* rdA0 = bufc + wr * 16384;                    // buf0, wave's A half
    const char* rdB0 = bufc + 32768 + (wc >> 1) * 16384;     // buf0, wave's B half
    const char* rdA1 = rdA0 + 65536;
    const char* rdB1 = rdB0 + 65536;

    floatx4 acc[8][4] = {};
    bf16x8 aF[8], bL[4], bH[4];

    const int KTn = K >> 6;   // K-tiles of 64

    // ---- prologue: tile0 fully + tile1 {B0,B1,A0}; tile1.A1 staged at first P1
    STAGE_A(0, 0, 0); STAGE_A(0, 0, 1); STAGE_B(0, 0, 0); STAGE_B(0, 0, 1);
    STAGE_B(1, 1, 0); STAGE_B(1, 1, 1); STAGE_A(1, 1, 0);
    VMCNT(6);
    BARF();

    for (int t = 0; t < KTn; t += 2) {
        const bool pf = (t + 2 < KTn);   // KTn even -> also guards t+3

        // ---- P1: read A0-3,B0-1 (buf0); stage (t+1).A1 -> buf1
        #pragma unroll
        for (int ii = 0; ii < 4; ++ii) { aF[ii*2+0] = RDA(rdA0, ii, ks0); aF[ii*2+1] = RDA(rdA0, ii, ks1); }
        #pragma unroll
        for (int jj = 0; jj < 2; ++jj) { bL[jj*2+0] = RDB(rdB0, jj, ks0); bL[jj*2+1] = RDB(rdB0, jj, ks1); }
        STAGE_A(1, t + 1, 1);
        BARF();
        MFMA_Q(0, 0, bL);
        BARF();

        // ---- P2: read B2-3 (buf0)
        #pragma unroll
        for (int jj = 0; jj < 2; ++jj) { bH[jj*2+0] = RDB(rdB0, 2 + jj, ks0); bH[jj*2+1] = RDB(rdB0, 2 + jj, ks1); }
        BARF();
        MFMA_Q(0, 2, bH);
        BARF();

        // ---- P3: read A4-7 (buf0); stage (t+2).B0 (buf0.B free after P2)
        #pragma unroll
        for (int ii = 0; ii < 4; ++ii) { aF[ii*2+0] = RDA(rdA0, 4 + ii, ks0); aF[ii*2+1] = RDA(rdA0, 4 + ii, ks1); }
        if (pf) STAGE_B(0, t + 2, 0);
        BARF();
        MFMA_Q(4, 0, bL);
        BARF();

        // ---- P4: stage (t+2).B1,(t+2).A0 (buf0.A free after P3); vmcnt gate for tile t+1
        if (pf) { STAGE_B(0, t + 2, 1); STAGE_A(0, t + 2, 0); }
        BARF();
        MFMA_Q(4, 2, bH);
        if (pf) { VMCNT(6); } else { VMCNT(0); }
        BARF();

        // ---- P5: read A0-3,B0-1 (buf1); stage (t+2).A1
        #pragma unroll
        for (int ii = 0; ii < 4; ++ii) { aF[ii*2+0] = RDA(rdA1, ii, ks0); aF[ii*2+1] = RDA(rdA1, ii, ks1); }
        #pragma unroll
        for (int jj = 0; jj < 2; ++jj) { bL[jj*2+0] = RDB(rdB1, jj, ks0); bL[jj*2+1] = RDB(rdB1, jj, ks1); }
        if (pf) STAGE_A(0, t + 2, 1);
        BARF();
        MFMA_Q(0, 0, bL);
        BARF();

        // ---- P6: read B2-3 (buf1)
        #pragma unroll
        for (int jj = 0; jj < 2; ++jj) { bH[jj*2+0] = RDB(rdB1, 2 + jj, ks0); bH[jj*2+1] = RDB(rdB1, 2 + jj, ks1); }
        BARF();
        MFMA_Q(0, 2, bH);
        BARF();

        // ---- P7: read A4-7 (buf1); stage (t+3).B0 (buf1.B free after P6)
        #pragma unroll
        for (int ii = 0; ii < 4; ++ii) { aF[ii*2+0] = RDA(rdA1, 4 + ii, ks0); aF[ii*2+1] = RDA(rdA1, 4 + ii, ks1); }
        if (pf) STAGE_B(1, t + 3, 0);
        BARF();
        MFMA_Q(4, 0, bL);
        BARF();

        // ---- P8: stage (t+3).B1,(t+3).A0 (buf1.A free after P7); vmcnt gate for tile t+2
        if (pf) { STAGE_B(1, t + 3, 1); STAGE_A(1, t + 3, 0); }
        BARF();
        MFMA_Q(4, 2, bH);
        VMCNT(6);
        BARF();
    }

    // ---------------- epilogue
    const int colb = n0 + wc * 64;
    const int rowb = m0 + wr * 128;
    if (MODE == 0) {
        #pragma unroll
        for (int i2 = 0; i2 < 8; ++i2)
            #pragma unroll
            for (int j2 = 0; j2 < 4; ++j2) {
                const int col = colb + j2 * 16 + li;
                const float bv = bias[col];
                #pragma unroll
                for (int r = 0; r < 4; ++r) {
                    const int row = rowb + i2 * 16 + quad * 4 + r;
                    Cf[(size_t)row * N + col] = acc[i2][j2][r] + bv;
                }
            }
    } else {
        // N = 6144: which = n0>>11 is block-uniform (256 | 2048)
        const int bb = m0 >> 11;
        const int which = n0 >> 11;
        #pragma unroll
        for (int i2 = 0; i2 < 8; ++i2)
            #pragma unroll
            for (int j2 = 0; j2 < 4; ++j2) {
                const int ng = colb + j2 * 16 + li;
                const float bv = bias[ng];
                const int e = ng & 2047, hh = e >> 7, dd = e & 127;
                const size_t bh = (size_t)(bb * 16 + hh);
                const int l0 = (rowb + i2 * 16 + quad * 4) & 2047;
                if (which == 2) {
                    ushort4 o4;
                    o4.x = f2bf(acc[i2][j2][0] + bv);
                    o4.y = f2bf(acc[i2][j2][1] + bv);
                    o4.z = f2bf(acc[i2][j2][2] + bv);
                    o4.w = f2bf(acc[i2][j2][3] + bv);
                    *(ushort4*)(vT_ws + (bh * 128 + dd) * 2048 + l0) = o4;
                } else {
                    unsigned short* dst = (which == 0) ? q_ws : k_ws;
                    #pragma unroll
                    for (int r = 0; r < 4; ++r)
                        dst[(bh * 2048 + (l0 + r)) * 128 + dd] = f2bf(acc[i2][j2][r] + bv);
                }
            }
    }
}

// ---------------------------------------------------------------- attention
// 256 thr = 4 waves per block; block = one 128-row q-tile of one (b,h).
// Wave owns 32 q-rows. 32x32x16 MFMA. S^T = K*Q^T (softmax lane-local),
// O^T = V^T * P^T with P transposed S->B-frag via register shuffles.
#define AP 8
__global__ __launch_bounds__(256, 2) void attn_kernel(
    const unsigned short* __restrict__ q_ws,
    const unsigned short* __restrict__ k_ws,
    const unsigned short* __restrict__ vT_ws,
    unsigned short* __restrict__ aout,
    const int* __restrict__ causal_ptr)
{
    __shared__ unsigned short Ksm[128][128 + AP];   // 34 KB (reused for O epilogue)
    __shared__ unsigned short Vsm[128][128 + AP];   // 34 KB, d-major (V^T)

    // balanced mapping: blocks c and c+256 sum to 17 tile-computes
    const int ord = blockIdx.x;
    int qt, bhid;
    if (ord < 256) { qt = ord >> 5;              bhid = ord & 31; }
    else           { qt = 15 - ((ord - 256) >> 5); bhid = ord & 31; }
    const int b = bhid >> 4, h = bhid & 15;

    const int tid = threadIdx.x;
    const int lane = tid & 63, w = tid >> 6;       // 4 waves
    const int lq = lane & 31;                      // q-col / row-in-tile
    const int half = lane >> 5;
    const size_t bh = (size_t)(b * 16 + h);
    const unsigned short* Qp = q_ws + bh * 2048 * 128;
    const unsigned short* Kp = k_ws + bh * 2048 * 128;
    const unsigned short* Vp = vT_ws + bh * 128 * 2048;
    const int causal = causal_ptr[0];
    const float scale = 0.08838834764831845f;      // 1/sqrt(128)

    // Q^T B-operand frags (persist): qf[s][j] = Q[qg][16s + 8*half + j]
    const int qg = qt * 128 + w * 32 + lq;
    bf16x8 qf[8];
    #pragma unroll
    for (int s = 0; s < 8; ++s)
        qf[s] = *(const bf16x8*)(Qp + (size_t)qg * 128 + s * 16 + half * 8);

    floatx16 O[4] = {};
    float m_i = -INFINITY, l_i = 0.f;

    const int myEnd = causal ? qt : 15;
    for (int kt = 0; kt <= myEnd; ++kt) {
        // stage K [key][d] and V^T [d][key] tiles: 2048 x 16B chunks
        #pragma unroll
        for (int c = 0; c < 8; ++c) {
            int chunk = c * 256 + tid;            // 0..2047
            int row = chunk >> 4;                 // 0..127
            int cc  = (chunk & 15) * 8;           // ushort col 0..120
            *(uint4*)(&Ksm[row][cc]) =
                *(const uint4*)(Kp + (size_t)(kt * 128 + row) * 128 + cc);
            *(uint4*)(&Vsm[row][cc]) =
                *(const uint4*)(Vp + (size_t)row * 2048 + kt * 128 + cc);
        }
        __syncthreads();

        // S^T[key][q]: 4 key-groups of 32; A = K rows, B = Q^T
        floatx16 S[4] = {};
        #pragma unroll
        for (int ct = 0; ct < 4; ++ct)
            #pragma unroll
            for (int s = 0; s < 8; ++s) {
                bf16x8 kf = *(const bf16x8*)(&Ksm[ct * 32 + lq][s * 16 + half * 8]);
                S[ct] = __builtin_amdgcn_mfma_f32_32x32x16_bf16(kf, qf[s], S[ct], 0, 0, 0);
            }

        // scale + causal mask; row stats are LANE-LOCAL (col of S^T = q)
        const bool diag = causal && (kt == qt);
        float mx = -INFINITY;
        #pragma unroll
        for (int ct = 0; ct < 4; ++ct)
            #pragma unroll
            for (int r = 0; r < 16; ++r) {
                float sv = S[ct][r] * scale;
                if (diag) {
                    int key = 32 * ct + (r & 3) + 8 * (r >> 2) + 4 * half;
                    if (kt * 128 + key > qg) sv = -INFINITY;
                }
                S[ct][r] = sv;
                mx = fmaxf(mx, sv);
            }
        mx = fmaxf(mx, __shfl_xor(mx, 32, 64));   // combine key-halves
        float m_new = fmaxf(m_i, mx);
        float m_use = (m_new == -INFINITY) ? 0.f : m_new;
        float alpha = __expf(m_i - m_use);

        float rs = 0.f;
        #pragma unroll
        for (int ct = 0; ct < 4; ++ct)
            #pragma unroll
            for (int r = 0; r < 16; ++r) {
                float p = __expf(S[ct][r] - m_use);
                S[ct][r] = p;
                rs += p;
            }
        rs += __shfl_xor(rs, 32, 64);
        l_i = l_i * alpha + rs;
        m_i = m_new;
        #pragma unroll
        for (int dt = 0; dt < 4; ++dt)
            #pragma unroll
            for (int r = 0; r < 16; ++r)
                O[dt][r] *= alpha;

        // P^T -> B-operand frags via register half-swap (no LDS round-trip)
        bf16x8 pfr[8];
        #pragma unroll
        for (int ct = 0; ct < 4; ++ct)
            #pragma unroll
            for (int h2 = 0; h2 < 2; ++h2) {
                int base = 8 * h2;
                unsigned int pk0 = pkbf(S[ct][base + 0], S[ct][base + 1]);
                unsigned int pk1 = pkbf(S[ct][base + 2], S[ct][base + 3]);
                unsigned int pk2 = pkbf(S[ct][base + 4], S[ct][base + 5]);
                unsigned int pk3 = pkbf(S[ct][base + 6], S[ct][base + 7]);
                unsigned int x0 = __shfl_xor((int)pk0, 32, 64);
                unsigned int x1 = __shfl_xor((int)pk1, 32, 64);
                unsigned int x2 = __shfl_xor((int)pk2, 32, 64);
                unsigned int x3 = __shfl_xor((int)pk3, 32, 64);
                union { unsigned int u[4]; bf16x8 v; } fr;
                fr.u[0] = half ? x2 : pk0;
                fr.u[1] = half ? x3 : pk1;
                fr.u[2] = half ? pk2 : x0;
                fr.u[3] = half ? pk3 : x1;
                pfr[ct * 2 + h2] = fr.v;
            }

        // O^T[d][q] += V^T * P^T; A = V^T rows (d), B = pfr
        #pragma unroll
        for (int dt = 0; dt < 4; ++dt)
            #pragma unroll
            for (int s = 0; s < 8; ++s) {
                bf16x8 vf = *(const bf16x8*)(&Vsm[dt * 32 + lq][s * 16 + half * 8]);
                O[dt] = __builtin_amdgcn_mfma_f32_32x32x16_bf16(vf, pfr[s], O[dt], 0, 0, 0);
            }
        __syncthreads();   // before next tile restages K/V
    }

    // epilogue: normalize, transpose O^T->[q][d] via Ksm, coalesced store
    const float invl = 1.0f / l_i;
    #pragma unroll
    for (int dt = 0; dt < 4; ++dt)
        #pragma unroll
        for (int g = 0; g < 4; ++g) {
            int dbase = dt * 32 + g * 8 + half * 4;
            ushort4 o4;
            o4.x = f2bf(O[dt][g * 4 + 0] * invl);
            o4.y = f2bf(O[dt][g * 4 + 1] * invl);
            o4.z = f2bf(O[dt][g * 4 + 2] * invl);
            o4.w = f2bf(O[dt][g * 4 + 3] * invl);
            *(ushort4*)(&Ksm[w * 32 + lq][dbase]) = o4;
        }
    __syncthreads();
    #pragma unroll
    for (int c = 0; c < 8; ++c) {
        int chunk = c * 256 + tid;                // 0..2047
        int row = chunk >> 4;                     // 0..127 (q within tile)
        int dc = (chunk & 15) * 8;
        uint4 v = *(const uint4*)(&Ksm[row][dc]);
        *(uint4*)(aout + ((size_t)b * 2048 + qt * 128 + row) * 2048 + h * 128 + dc) = v;
    }
}

// ---------------------------------------------------------------- launch
extern "C" void kernel_launch(void* const* d_in, const int* in_sizes, int n_in,
                              void* d_out, int out_size, void* d_ws, size_t ws_size,
                              hipStream_t stream) {
    const float* x     = (const float*)d_in[0];
    const float* w_in  = (const float*)d_in[1];
    const float* b_in  = (const float*)d_in[2];
    const float* w_out = (const float*)d_in[3];
    const float* b_out = (const float*)d_in[4];
    const int* causal  = (const int*)d_in[5];

    char* ws = (char*)d_ws;
    unsigned short* xb    = (unsigned short*)ws; ws += (size_t)4096 * 2048 * 2;
    unsigned short* wb    = (unsigned short*)ws; ws += (size_t)6144 * 2048 * 2;
    unsigned short* wob   = (unsigned short*)ws; ws += (size_t)2048 * 2048 * 2;
    unsigned short* q_ws  = (unsigned short*)ws; ws += (size_t)32 * 2048 * 128 * 2;
    unsigned short* k_ws  = (unsigned short*)ws; ws += (size_t)32 * 2048 * 128 * 2;
    unsigned short* vT_ws = (unsigned short*)ws; ws += (size_t)32 * 2048 * 128 * 2;
    unsigned short* aout  = (unsigned short*)ws; ws += (size_t)4096 * 2048 * 2;

    // allow 128 KiB dynamic LDS for the 8-phase GEMMs (one-time)
    static int once = []() {
        auto* f0 = gemm8p<0>;
        auto* f1 = gemm8p<1>;
        hipFuncSetAttribute((const void*)f0,
            hipFuncAttributeMaxDynamicSharedMemorySize, 131072);
        hipFuncSetAttribute((const void*)f1,
            hipFuncAttributeMaxDynamicSharedMemorySize, 131072);
        return 0;
    }();
    (void)once;

    cast_f32_bf16<<<8192, 256, 0, stream>>>(x, xb, 4096 * 2048);
    cast_f32_bf16<<<12288, 256, 0, stream>>>(w_in, wb, 6144 * 2048);
    cast_f32_bf16<<<4096, 256, 0, stream>>>(w_out, wob, 2048 * 2048);

    // QKV: M=4096, N=6144 -> grid 16*24 = 384
    gemm8p<1><<<384, 512, 131072, stream>>>(
        xb, wb, b_in, nullptr, q_ws, k_ws, vT_ws, 4096, 6144, 2048);

    attn_kernel<<<512, 256, 0, stream>>>(
        q_ws, k_ws, vT_ws, aout, causal);

    // out-proj: M=4096, N=2048 -> grid 16*8 = 128
    gemm8p<0><<<128, 512, 131072, stream>>>(
        aout, wob, b_out, (float*)d_out, nullptr, nullptr, nullptr,
        4096, 2048, 2048);
}

// Round 2
// 383.371 us; speedup vs baseline: 1.1331x; 1.0287x over previous
//
#include <hip/hip_runtime.h>
#include <hip/hip_bf16.h>
#include <math.h>

typedef __attribute__((ext_vector_type(4))) float floatx4;
typedef __attribute__((ext_vector_type(16))) float floatx16;
typedef __attribute__((ext_vector_type(8))) __bf16 bf16x8;

__device__ __forceinline__ unsigned short f2bf(float f) {
    union { float f; unsigned int u; } v; v.f = f;
    unsigned int u = v.u;
    u += 0x7FFFu + ((u >> 16) & 1u);          // round-to-nearest-even
    return (unsigned short)(u >> 16);
}

__device__ __forceinline__ unsigned int pkbf(float a, float b) {
    return (unsigned int)f2bf(a) | ((unsigned int)f2bf(b) << 16);  // low16=a
}

// async global->LDS, 16B per lane; lds base must be wave-uniform
__device__ __forceinline__ void gl_lds16(const void* g, void* l) {
    __builtin_amdgcn_global_load_lds(
        (const __attribute__((address_space(1))) void*)g,
        (__attribute__((address_space(3))) void*)l, 16, 0, 0);
}

// ---------------------------------------------------------------- cast kernel
__global__ void cast_f32_bf16(const float* __restrict__ in,
                              unsigned short* __restrict__ out, int n) {
    int i = (blockIdx.x * blockDim.x + threadIdx.x) * 4;
    if (i + 4 <= n) {
        float4 f = *(const float4*)(in + i);
        ushort4 o;
        o.x = f2bf(f.x); o.y = f2bf(f.y); o.z = f2bf(f.z); o.w = f2bf(f.w);
        *(ushort4*)(out + i) = o;
    }
}

// ---------------------------------------------------------------- GEMM (NT)
// C[M,N] = A[M,K] * B[N,K]^T + bias[N]
// BM=256 x BN=128 tile, BK=64, 8 waves (2M x 4N, per-wave 128x32).
// 4-phase counted-vmcnt schedule (T1+T2+T3/T4+T5). LDS: 2 x 48KB = 96 KiB.
// Grid packs perfectly: QKV 16x48=768 (3 rounds), out-proj 16x16=256 (1 round).
// MODE 0: fp32 C.  MODE 1: bf16 via LDS-transpose epilogue to q/k/vT.

#define VMCNT(n) asm volatile("s_waitcnt vmcnt(" #n ")" ::: "memory")
#define LGKM0()  asm volatile("s_waitcnt lgkmcnt(0)" ::: "memory")
#define BARF()   do { asm volatile("" ::: "memory"); __builtin_amdgcn_s_barrier(); \
                      asm volatile("" ::: "memory"); } while (0)

// A-tile: 256 rows x 64 K, two 128-row halves of 16 KB; 2 loads/thread/half.
#define STAGE_A4(bsel, tt, h) do { \
    const unsigned short* _s = Ab + (size_t)((h) * 128 + rstage) * K + (tt) * 64 + scol; \
    char* _d = bufc + (bsel) * 49152 + (h) * 16384 + wid * 1024; \
    gl_lds16(_s, _d); \
    gl_lds16(_s + (size_t)64 * K, _d + 8192); \
} while (0)

// B-tile: 128 rows x 64 K, two 64-row halves of 8 KB; 1 load/thread/half.
#define STAGE_B4(bsel, tt, h) do { \
    const unsigned short* _s = Bb + (size_t)((h) * 64 + rstage) * K + (tt) * 64 + scol; \
    char* _d = bufc + (bsel) * 49152 + 32768 + (h) * 8192 + wid * 1024; \
    gl_lds16(_s, _d); \
} while (0)

#define STAGE_TILE(bsel, tt) do { \
    STAGE_A4(bsel, tt, 0); STAGE_A4(bsel, tt, 1); \
    STAGE_B4(bsel, tt, 0); STAGE_B4(bsel, tt, 1); \
} while (0)   /* 6 vm-instructions total */

// swizzled LDS fragment reads
#define RDA(base, ii, kse) (*(const bf16x8*)((base) + (ii) * 2048 + rdoffA + (kse)))
#define RDB(base, jj, kse) (*(const bf16x8*)((base) + (jj) * 2048 + rdoffB + (kse)))

// one cluster: 4 row-frags x 2 col-frags x K=64 = 16 MFMA
#define MFMA_C(iofs) do { \
    __builtin_amdgcn_s_setprio(1); \
    _Pragma("unroll") \
    for (int ii = 0; ii < 4; ++ii) { \
        _Pragma("unroll") \
        for (int jj = 0; jj < 2; ++jj) { \
            acc[(iofs) + ii][jj] = __builtin_amdgcn_mfma_f32_16x16x32_bf16( \
                aF[((iofs) + ii) * 2 + 0], bL[jj * 2 + 0], acc[(iofs) + ii][jj], 0, 0, 0); \
            acc[(iofs) + ii][jj] = __builtin_amdgcn_mfma_f32_16x16x32_bf16( \
                aF[((iofs) + ii) * 2 + 1], bL[jj * 2 + 1], acc[(iofs) + ii][jj], 0, 0, 0); \
        } } \
    __builtin_amdgcn_s_setprio(0); \
} while (0)

template<int MODE>
__global__ __launch_bounds__(512, 2) void gemm4p(
    const unsigned short* __restrict__ A,
    const unsigned short* __restrict__ B,
    const float* __restrict__ bias,
    float* __restrict__ Cf,
    unsigned short* __restrict__ q_ws,
    unsigned short* __restrict__ k_ws,
    unsigned short* __restrict__ vT_ws,
    int M, int N, int K)
{
    extern __shared__ char ldsc[];
    char* const bufc = ldsc;

    // T1: bijective XCD swizzle (nwg % 8 == 0 at both call sites); within an
    // XCD chunk by cycles fastest -> B-panel resident in that XCD's L2.
    const int nby = M >> 8;                  // 256-row M tiles
    const int nwg = gridDim.x;
    const int qq = nwg >> 3;
    const int wg = (blockIdx.x & 7) * qq + (blockIdx.x >> 3);
    const int by = wg % nby, bx = wg / nby;
    const int m0 = by << 8, n0 = bx << 7;    // 128-col N tiles

    const int tid = threadIdx.x;
    const int lane = tid & 63, wid = tid >> 6;
    const int li = lane & 15, quad = lane >> 4;
    const int wr = wid >> 2, wc = wid & 3;   // 2 x 4 wave grid

    // staging geometry (constant per thread)
    const int rstage = tid >> 3;                               // 0..63
    const int scol = (((tid & 7) ^ ((tid >> 3) & 7)) << 3);    // swizzled src col
    const unsigned short* Ab = A + (size_t)m0 * K;
    const unsigned short* Bb = B + (size_t)n0 * K;

    // read-side swizzle constants
    const int swz = (lane & 7) << 4;
    const int ks0 = ((quad << 4)     ) ^ swz;
    const int ks1 = ((quad << 4) + 64) ^ swz;
    const int rdoffA = li * 128;
    const int rdoffB = li * 128 + ((wc & 1) << 12);   // +32 rows within B half

    const char* rdA0 = bufc + wr * 16384;             // wave's 128-row A half
    const char* rdB0 = bufc + 32768 + (wc >> 1) * 8192;
    const char* rdA1 = rdA0 + 49152;
    const char* rdB1 = rdB0 + 49152;

    floatx4 acc[8][2] = {};
    bf16x8 aF[16], bL[4];

    const int KTn = K >> 6;   // K-tiles of 64 (=32 here), even

    // ---- prologue: stage tile0 -> buf0, tile1 -> buf1 (6+6 loads)
    STAGE_TILE(0, 0);
    STAGE_TILE(1, 1);
    VMCNT(6);                 // drain tile0
    BARF();

    for (int t = 0; t < KTn; t += 2) {
        const bool pf = (t + 2 < KTn);   // KTn even -> guards t+3 too

        // ---- P1: read buf0 fully (A0-7 x2ks = 16, B 4)
        #pragma unroll
        for (int ii = 0; ii < 8; ++ii) { aF[ii*2+0] = RDA(rdA0, ii, ks0); aF[ii*2+1] = RDA(rdA0, ii, ks1); }
        #pragma unroll
        for (int jj = 0; jj < 2; ++jj) { bL[jj*2+0] = RDB(rdB0, jj, ks0); bL[jj*2+1] = RDB(rdB0, jj, ks1); }
        BARF();
        MFMA_C(0);
        LGKM0();              // all buf0 reads retired before stages overwrite it
        BARF();

        // ---- P2: stage (t+2) -> buf0 (free after P1); gate buf1 for P3
        if (pf) STAGE_TILE(0, t + 2);
        BARF();
        MFMA_C(4);
        if (pf) { VMCNT(6); } else { VMCNT(0); }   // drain tile t+1
        BARF();

        // ---- P3: read buf1 fully
        #pragma unroll
        for (int ii = 0; ii < 8; ++ii) { aF[ii*2+0] = RDA(rdA1, ii, ks0); aF[ii*2+1] = RDA(rdA1, ii, ks1); }
        #pragma unroll
        for (int jj = 0; jj < 2; ++jj) { bL[jj*2+0] = RDB(rdB1, jj, ks0); bL[jj*2+1] = RDB(rdB1, jj, ks1); }
        BARF();
        MFMA_C(0);
        LGKM0();
        BARF();

        // ---- P4: stage (t+3) -> buf1; gate buf0 (tile t+2) for next P1
        if (pf) STAGE_TILE(1, t + 3);
        BARF();
        MFMA_C(4);
        if (pf) { VMCNT(6); } else { VMCNT(0); }   // drain tile t+2
        BARF();
    }

    // ---------------- epilogue
    const int colb = wc * 32;
    const int rowb = wr * 128;
    if (MODE == 0) {
        #pragma unroll
        for (int i2 = 0; i2 < 8; ++i2)
            #pragma unroll
            for (int j2 = 0; j2 < 2; ++j2) {
                const int col = n0 + colb + j2 * 16 + li;
                const float bv = bias[col];
                #pragma unroll
                for (int r = 0; r < 4; ++r) {
                    const int row = m0 + rowb + i2 * 16 + quad * 4 + r;
                    Cf[(size_t)row * N + col] = acc[i2][j2][r] + bv;
                }
            }
    } else {
        // N=6144: block covers exactly one head-chunk. which/h block-uniform.
        const int which = bx >> 4;           // 0:q 1:k 2:vT
        const int hh = bx & 15;
        const int lbase = m0 & 2047;
        const size_t bh = (size_t)((m0 >> 11) * 16 + hh);
        // LDS-transpose epilogue (reuses pipeline LDS; all reads retired)
        if (which == 2) {
            unsigned short (*Lv)[264] = (unsigned short(*)[264])ldsc;   // 67.6 KB
            #pragma unroll
            for (int i2 = 0; i2 < 8; ++i2)
                #pragma unroll
                for (int j2 = 0; j2 < 2; ++j2) {
                    const int col = colb + j2 * 16 + li;       // d
                    const float bv = bias[n0 + col];
                    #pragma unroll
                    for (int r = 0; r < 4; ++r) {
                        const int row = rowb + i2 * 16 + quad * 4 + r;   // l
                        Lv[col][row] = f2bf(acc[i2][j2][r] + bv);
                    }
                }
            __syncthreads();
            #pragma unroll
            for (int c = 0; c < 8; ++c) {
                int chunk = c * 512 + tid;           // 0..4095
                int d = chunk >> 5;                  // 0..127
                int ls = (chunk & 31) * 8;           // 0..248
                *(uint4*)(vT_ws + (bh * 128 + d) * 2048 + lbase + ls) =
                    *(const uint4*)&Lv[d][ls];
            }
        } else {
            unsigned short (*Lq)[136] = (unsigned short(*)[136])ldsc;   // 69.6 KB
            #pragma unroll
            for (int i2 = 0; i2 < 8; ++i2)
                #pragma unroll
                for (int j2 = 0; j2 < 2; ++j2) {
                    const int col = colb + j2 * 16 + li;       // d
                    const float bv = bias[n0 + col];
                    #pragma unroll
                    for (int r = 0; r < 4; ++r) {
                        const int row = rowb + i2 * 16 + quad * 4 + r;   // l
                        Lq[row][col] = f2bf(acc[i2][j2][r] + bv);
                    }
                }
            __syncthreads();
            unsigned short* dst = which ? k_ws : q_ws;
            #pragma unroll
            for (int c = 0; c < 8; ++c) {
                int chunk = c * 512 + tid;           // 0..4095
                int row = chunk >> 4;                // 0..255 (l)
                int dc = (chunk & 15) * 8;           // 0..120 (d)
                *(uint4*)(dst + (bh * 2048 + lbase + row) * (size_t)128 + dc) =
                    *(const uint4*)&Lq[row][dc];
            }
        }
    }
}

// ---------------------------------------------------------------- attention
// 256 thr = 4 waves per block; block = one 128-row q-tile of one (b,h).
// Wave owns 32 q-rows. 32x32x16 MFMA. S^T = K*Q^T (softmax lane-local),
// O^T = V^T * P^T with P transposed S->B-frag via register shuffles.
#define AP 8
__global__ __launch_bounds__(256, 2) void attn_kernel(
    const unsigned short* __restrict__ q_ws,
    const unsigned short* __restrict__ k_ws,
    const unsigned short* __restrict__ vT_ws,
    unsigned short* __restrict__ aout,
    const int* __restrict__ causal_ptr)
{
    __shared__ unsigned short Ksm[128][128 + AP];   // 34 KB (reused for O epilogue)
    __shared__ unsigned short Vsm[128][128 + AP];   // 34 KB, d-major (V^T)

    // balanced mapping: blocks c and c+256 sum to 17 tile-computes
    const int ord = blockIdx.x;
    int qt, bhid;
    if (ord < 256) { qt = ord >> 5;              bhid = ord & 31; }
    else           { qt = 15 - ((ord - 256) >> 5); bhid = ord & 31; }
    const int b = bhid >> 4, h = bhid & 15;

    const int tid = threadIdx.x;
    const int lane = tid & 63, w = tid >> 6;       // 4 waves
    const int lq = lane & 31;                      // q-col / row-in-tile
    const int half = lane >> 5;
    const size_t bh = (size_t)(b * 16 + h);
    const unsigned short* Qp = q_ws + bh * 2048 * 128;
    const unsigned short* Kp = k_ws + bh * 2048 * 128;
    const unsigned short* Vp = vT_ws + bh * 128 * 2048;
    const int causal = causal_ptr[0];
    const float scale = 0.08838834764831845f;      // 1/sqrt(128)

    // Q^T B-operand frags (persist): qf[s][j] = Q[qg][16s + 8*half + j]
    const int qg = qt * 128 + w * 32 + lq;
    bf16x8 qf[8];
    #pragma unroll
    for (int s = 0; s < 8; ++s)
        qf[s] = *(const bf16x8*)(Qp + (size_t)qg * 128 + s * 16 + half * 8);

    floatx16 O[4] = {};
    float m_i = -INFINITY, l_i = 0.f;

    const int myEnd = causal ? qt : 15;
    for (int kt = 0; kt <= myEnd; ++kt) {
        // stage K [key][d] and V^T [d][key] tiles: 2048 x 16B chunks
        #pragma unroll
        for (int c = 0; c < 8; ++c) {
            int chunk = c * 256 + tid;            // 0..2047
            int row = chunk >> 4;                 // 0..127
            int cc  = (chunk & 15) * 8;           // ushort col 0..120
            *(uint4*)(&Ksm[row][cc]) =
                *(const uint4*)(Kp + (size_t)(kt * 128 + row) * 128 + cc);
            *(uint4*)(&Vsm[row][cc]) =
                *(const uint4*)(Vp + (size_t)row * 2048 + kt * 128 + cc);
        }
        __syncthreads();

        // S^T[key][q]: 4 key-groups of 32; A = K rows, B = Q^T
        floatx16 S[4] = {};
        #pragma unroll
        for (int ct = 0; ct < 4; ++ct)
            #pragma unroll
            for (int s = 0; s < 8; ++s) {
                bf16x8 kf = *(const bf16x8*)(&Ksm[ct * 32 + lq][s * 16 + half * 8]);
                S[ct] = __builtin_amdgcn_mfma_f32_32x32x16_bf16(kf, qf[s], S[ct], 0, 0, 0);
            }

        // scale + causal mask; row stats are LANE-LOCAL (col of S^T = q)
        const bool diag = causal && (kt == qt);
        float mx = -INFINITY;
        #pragma unroll
        for (int ct = 0; ct < 4; ++ct)
            #pragma unroll
            for (int r = 0; r < 16; ++r) {
                float sv = S[ct][r] * scale;
                if (diag) {
                    int key = 32 * ct + (r & 3) + 8 * (r >> 2) + 4 * half;
                    if (kt * 128 + key > qg) sv = -INFINITY;
                }
                S[ct][r] = sv;
                mx = fmaxf(mx, sv);
            }
        mx = fmaxf(mx, __shfl_xor(mx, 32, 64));   // combine key-halves
        float m_new = fmaxf(m_i, mx);
        float m_use = (m_new == -INFINITY) ? 0.f : m_new;
        float alpha = __expf(m_i - m_use);

        float rs = 0.f;
        #pragma unroll
        for (int ct = 0; ct < 4; ++ct)
            #pragma unroll
            for (int r = 0; r < 16; ++r) {
                float p = __expf(S[ct][r] - m_use);
                S[ct][r] = p;
                rs += p;
            }
        rs += __shfl_xor(rs, 32, 64);
        l_i = l_i * alpha + rs;
        m_i = m_new;
        #pragma unroll
        for (int dt = 0; dt < 4; ++dt)
            #pragma unroll
            for (int r = 0; r < 16; ++r)
                O[dt][r] *= alpha;

        // P^T -> B-operand frags via register half-swap (no LDS round-trip)
        bf16x8 pfr[8];
        #pragma unroll
        for (int ct = 0; ct < 4; ++ct)
            #pragma unroll
            for (int h2 = 0; h2 < 2; ++h2) {
                int base = 8 * h2;
                unsigned int pk0 = pkbf(S[ct][base + 0], S[ct][base + 1]);
                unsigned int pk1 = pkbf(S[ct][base + 2], S[ct][base + 3]);
                unsigned int pk2 = pkbf(S[ct][base + 4], S[ct][base + 5]);
                unsigned int pk3 = pkbf(S[ct][base + 6], S[ct][base + 7]);
                unsigned int x0 = __shfl_xor((int)pk0, 32, 64);
                unsigned int x1 = __shfl_xor((int)pk1, 32, 64);
                unsigned int x2 = __shfl_xor((int)pk2, 32, 64);
                unsigned int x3 = __shfl_xor((int)pk3, 32, 64);
                union { unsigned int u[4]; bf16x8 v; } fr;
                fr.u[0] = half ? x2 : pk0;
                fr.u[1] = half ? x3 : pk1;
                fr.u[2] = half ? pk2 : x0;
                fr.u[3] = half ? pk3 : x1;
                pfr[ct * 2 + h2] = fr.v;
            }

        // O^T[d][q] += V^T * P^T; A = V^T rows (d), B = pfr
        #pragma unroll
        for (int dt = 0; dt < 4; ++dt)
            #pragma unroll
            for (int s = 0; s < 8; ++s) {
                bf16x8 vf = *(const bf16x8*)(&Vsm[dt * 32 + lq][s * 16 + half * 8]);
                O[dt] = __builtin_amdgcn_mfma_f32_32x32x16_bf16(vf, pfr[s], O[dt], 0, 0, 0);
            }
        __syncthreads();   // before next tile restages K/V
    }

    // epilogue: normalize, transpose O^T->[q][d] via Ksm, coalesced store
    const float invl = 1.0f / l_i;
    #pragma unroll
    for (int dt = 0; dt < 4; ++dt)
        #pragma unroll
        for (int g = 0; g < 4; ++g) {
            int dbase = dt * 32 + g * 8 + half * 4;
            ushort4 o4;
            o4.x = f2bf(O[dt][g * 4 + 0] * invl);
            o4.y = f2bf(O[dt][g * 4 + 1] * invl);
            o4.z = f2bf(O[dt][g * 4 + 2] * invl);
            o4.w = f2bf(O[dt][g * 4 + 3] * invl);
            *(ushort4*)(&Ksm[w * 32 + lq][dbase]) = o4;
        }
    __syncthreads();
    #pragma unroll
    for (int c = 0; c < 8; ++c) {
        int chunk = c * 256 + tid;                // 0..2047
        int row = chunk >> 4;                     // 0..127 (q within tile)
        int dc = (chunk & 15) * 8;
        uint4 v = *(const uint4*)(&Ksm[row][dc]);
        *(uint4*)(aout + ((size_t)b * 2048 + qt * 128 + row) * 2048 + h * 128 + dc) = v;
    }
}

// ---------------------------------------------------------------- launch
extern "C" void kernel_launch(void* const* d_in, const int* in_sizes, int n_in,
                              void* d_out, int out_size, void* d_ws, size_t ws_size,
                              hipStream_t stream) {
    const float* x     = (const float*)d_in[0];
    const float* w_in  = (const float*)d_in[1];
    const float* b_in  = (const float*)d_in[2];
    const float* w_out = (const float*)d_in[3];
    const float* b_out = (const float*)d_in[4];
    const int* causal  = (const int*)d_in[5];

    char* ws = (char*)d_ws;
    unsigned short* xb    = (unsigned short*)ws; ws += (size_t)4096 * 2048 * 2;
    unsigned short* wb    = (unsigned short*)ws; ws += (size_t)6144 * 2048 * 2;
    unsigned short* wob   = (unsigned short*)ws; ws += (size_t)2048 * 2048 * 2;
    unsigned short* q_ws  = (unsigned short*)ws; ws += (size_t)32 * 2048 * 128 * 2;
    unsigned short* k_ws  = (unsigned short*)ws; ws += (size_t)32 * 2048 * 128 * 2;
    unsigned short* vT_ws = (unsigned short*)ws; ws += (size_t)32 * 2048 * 128 * 2;
    unsigned short* aout  = (unsigned short*)ws; ws += (size_t)4096 * 2048 * 2;

    // allow 96 KiB dynamic LDS for the 4-phase GEMMs (one-time)
    static int once = []() {
        auto* f0 = gemm4p<0>;
        auto* f1 = gemm4p<1>;
        hipFuncSetAttribute((const void*)f0,
            hipFuncAttributeMaxDynamicSharedMemorySize, 98304);
        hipFuncSetAttribute((const void*)f1,
            hipFuncAttributeMaxDynamicSharedMemorySize, 98304);
        return 0;
    }();
    (void)once;

    cast_f32_bf16<<<8192, 256, 0, stream>>>(x, xb, 4096 * 2048);
    cast_f32_bf16<<<12288, 256, 0, stream>>>(w_in, wb, 6144 * 2048);
    cast_f32_bf16<<<4096, 256, 0, stream>>>(w_out, wob, 2048 * 2048);

    // QKV: M=4096, N=6144 -> grid 16*48 = 768 = 3 full rounds
    gemm4p<1><<<768, 512, 98304, stream>>>(
        xb, wb, b_in, nullptr, q_ws, k_ws, vT_ws, 4096, 6144, 2048);

    attn_kernel<<<512, 256, 0, stream>>>(
        q_ws, k_ws, vT_ws, aout, causal);

    // out-proj: M=4096, N=2048 -> grid 16*16 = 256 = 1 full round
    gemm4p<0><<<256, 512, 98304, stream>>>(
        aout, wob, b_out, (float*)d_out, nullptr, nullptr, nullptr,
        4096, 2048, 2048);
}